// Round 9
// baseline (82.417 us; speedup 1.0000x reference)
//
#include <hip/hip_runtime.h>
#include <hip/hip_bf16.h>

// Shapes: M=128, H=256, F=256, T=4, I=2, NSEM=57
#define M_ 128
#define H_ 256
#define F_ 256
#define T_ 4
#define NSEM_ 57

typedef __attribute__((ext_vector_type(8))) short bf16x8;
typedef __attribute__((ext_vector_type(4))) float f32x4;

__device__ __forceinline__ float4 ld4(const float* p) { return *reinterpret_cast<const float4*>(p); }
__device__ __forceinline__ void st4(float* p, float4 v) { *reinterpret_cast<float4*>(p) = v; }
__device__ __forceinline__ float4 add4(float4 a, float4 b) { return make_float4(a.x+b.x, a.y+b.y, a.z+b.z, a.w+b.w); }
__device__ __forceinline__ float4 relu4(float4 a) { return make_float4(fmaxf(a.x,0.f), fmaxf(a.y,0.f), fmaxf(a.z,0.f), fmaxf(a.w,0.f)); }
__device__ __forceinline__ float4 fma4(float s, float4 w, float4 c) { return make_float4(fmaf(s,w.x,c.x), fmaf(s,w.y,c.y), fmaf(s,w.z,c.z), fmaf(s,w.w,c.w)); }

__device__ __forceinline__ unsigned short f2bfu(float x) {
  unsigned u = __float_as_uint(x);
  return (unsigned short)((u + 0x7FFFu + ((u >> 16) & 1u)) >> 16);  // RNE
}
__device__ __forceinline__ unsigned pack2(float lo, float hi) {
  return (unsigned)f2bfu(lo) | ((unsigned)f2bfu(hi) << 16);
}

// ---------------------------------------------------------------------------
// K1: parent partial matmul + W-frag bf16 packing (LDS-staged, coalesced).
// grid 1024 = 32 col-blocks x 32 k-chunks (8 k each), 256 thr.
// ---------------------------------------------------------------------------
__global__ void __launch_bounds__(256) k_parent(
    const float* __restrict__ pf, const float* __restrict__ Wp,
    const float* __restrict__ Wop, float* __restrict__ part,
    unsigned short* __restrict__ W36F, unsigned short* __restrict__ W768F)
{
  const int t = threadIdx.x;
  __shared__ float spf[8];
  __shared__ float tile[16][17];

  // fb_global = b>>1 in [0, 512): [0,128) -> W36F (it0), [128,512) -> W768F.
  const int fbg = blockIdx.x >> 1;
  const int half = blockIdx.x & 1;
  const bool it0 = fbg < 128;
  const int fb = it0 ? fbg : fbg - 128;
  const int kk = fb >> 4, ct = fb & 15;
  const int base_k = kk * 32 + half * 16;
  int row_base;
  if (it0) row_base = 512 + base_k;                 // W3_0
  else row_base = (base_k < 256) ? 512 + base_k     // W3_1
                : (base_k < 512 ? base_k : base_k - 512);  // W2_1 / W1_1
  const float* wsrc = Wop + (it0 ? 0 : 197632);
  {
    const int r = t >> 4, c = t & 15;
    tile[r][c] = wsrc[(size_t)(row_base + r) * 256 + ct * 16 + c];
  }

  const int cb = (blockIdx.x & 31) * 1024 + t * 4;
  const int kc = blockIdx.x >> 5;
  if (t < 8) spf[t] = pf[kc * 8 + t];
  __syncthreads();
  const float* w = Wp + (size_t)kc * 8 * 32768 + cb;
  float4 acc = make_float4(0.f, 0.f, 0.f, 0.f);
  #pragma unroll
  for (int k = 0; k < 8; ++k)
    acc = fma4(spf[k], ld4(w + (size_t)k * 32768), acc);
  st4(&part[kc * 32768 + cb], acc);

  {
    const int k_local = ((t >> 7) << 3) + (t & 7);
    const int h_local = (t >> 3) & 15;
    const int e = half * 256 + t;
    unsigned short v = f2bfu(tile[k_local][h_local]);
    if (it0) W36F[fb * 512 + e] = v;
    else     W768F[fb * 512 + e] = v;
  }
}

// ---------------------------------------------------------------------------
// K2: stage1 = combine(32 partials, once per m) + A/B/a1/a2(it0) + exists +
// zero cf1/cf2. grid 128 (m) x 512 thr: 8 wave-groups = 4 streams x 2 K-halves.
// ---------------------------------------------------------------------------
__global__ void __launch_bounds__(512) k_stage1(
    const float* __restrict__ part, const float* __restrict__ bp,
    const float* __restrict__ Wel, const float* __restrict__ Wop0,
    const float* __restrict__ Wex, const float* __restrict__ bex,
    float* __restrict__ cf0, float* __restrict__ A, float* __restrict__ B,
    float* __restrict__ a1, float* __restrict__ a2,
    float* __restrict__ cf1, float* __restrict__ cf2,
    float* __restrict__ out_ex)
{
  const int m = blockIdx.x;
  const int t = threadIdx.x;
  const int tt = t & 255, half = t >> 8;
  __shared__ float sall[256];
  __shared__ float red[8][256];
  __shared__ float redE[4];

  // zero atomicMax targets (poison/stale-replay safety)
  (half ? cf2 : cf1)[m * 256 + tt] = 0.f;

  if (half == 0) {
    float pv[32];
    #pragma unroll
    for (int q = 0; q < 32; ++q) pv[q] = part[q * 32768 + m * 256 + tt];
    float v = bp[m * 256 + tt];
    #pragma unroll
    for (int q = 0; q < 32; ++q) v += pv[q];
    v = fmaxf(v, 0.f);
    sall[tt] = v;
    cf0[m * 256 + tt] = v;
    float p = v * Wex[tt];
    #pragma unroll
    for (int off = 32; off > 0; off >>= 1) p += __shfl_xor(p, off);
    if ((tt & 63) == 0) redE[tt >> 6] = p;
  }
  __syncthreads();

  // 8 wave-groups: stream s = kg&3 in {A, B, a1, a2}; K-half = kg>>2
  const int kg = t >> 6, s = kg & 3, kh = kg >> 2;
  const int hq = (t & 63) << 2, k0 = kh * 128;
  const float* W = (s == 0) ? Wel : (s == 1) ? Wel + 65536
                 : (s == 2) ? Wop0 : Wop0 + 65536;
  float4 acc = make_float4(0.f, 0.f, 0.f, 0.f);
  #pragma unroll 8
  for (int k = k0; k < k0 + 128; ++k)
    acc = fma4(sall[k], ld4(W + k * 256 + hq), acc);
  st4(&red[kg][hq], acc);
  __syncthreads();
  if (kg < 4) {
    float4 r = add4(ld4(&red[kg][hq]), ld4(&red[kg + 4][hq]));
    float* dst = (kg == 0) ? A : (kg == 1) ? B : (kg == 2) ? a1 : a2;
    st4(&dst[m * 256 + hq], r);
  }
  if (t == 0)
    out_ex[m] = redE[0] + redE[1] + redE[2] + redE[3] + bex[0];
}

// ---------------------------------------------------------------------------
// K3: gemm0, 64 j-rows per block (halves W36F L2 traffic vs 32-row tiles).
// grid 256 = (i, j-half), 512 thr = 8 waves; EL tile 64x256 bf16 (32 KB LDS,
// XOR-swizzled); exact fp32 ee computed in-block and written once.
// Epilogue masked relu-max -> atomicMax into cf1.
// ---------------------------------------------------------------------------
__global__ void __launch_bounds__(512) k_gemm0(
    const float* __restrict__ Arow, const float* __restrict__ Brow,
    const float* __restrict__ bel, const unsigned short* __restrict__ W36F,
    const float* __restrict__ Wee, const float* __restrict__ bee,
    const float* __restrict__ a1, const float* __restrict__ a2,
    const float* __restrict__ Wop0, const float* __restrict__ bop0,
    const float* __restrict__ exlog,
    float* __restrict__ ee_g, float* __restrict__ cf1)
{
  const int i  = blockIdx.x >> 1;
  const int jh = blockIdx.x & 1;
  const int t  = threadIdx.x;
  const int w  = t >> 6;
  const int l  = t & 63;
  __shared__ char sEL[64 * 512];
  __shared__ float see[64][4];
  __shared__ float sexf[64];

  const bool exi = exlog[i] > 0.f;
  const int lr = l & 15, lk = l >> 4;
  const int c0 = w * 32 + lr, c1 = c0 + 16;
  const float b10 = a1[i * 256 + c0] + bop0[c0];
  const float b11 = a1[i * 256 + c1] + bop0[c1];
  float w40[4], w41[4];
  #pragma unroll
  for (int q = 0; q < 4; ++q) {
    w40[q] = Wop0[(768 + q) * 256 + c0];
    w41[q] = Wop0[(768 + q) * 256 + c1];
  }

  // ---- stage EL tile (row = t>>3, 32 k's at (t&7)*32) + ee + pack bf16
  {
    const int row = t >> 3;        // 0..63
    const int sub = t & 7;
    const int kb  = sub * 32;
    const float* Ap  = Arow + i * 256 + kb;
    const float* Bp  = Brow + (jh * 64 + row) * 256 + kb;
    const float* blp = bel + kb;
    float e[32];
    #pragma unroll
    for (int q = 0; q < 32; q += 4) {
      float4 av = ld4(Ap + q), bv = ld4(Bp + q), lv = ld4(blp + q);
      e[q+0] = fmaxf(av.x + bv.x + lv.x, 0.f);
      e[q+1] = fmaxf(av.y + bv.y + lv.y, 0.f);
      e[q+2] = fmaxf(av.z + bv.z + lv.z, 0.f);
      e[q+3] = fmaxf(av.w + bv.w + lv.w, 0.f);
    }
    float s[4] = {0.f, 0.f, 0.f, 0.f};
    #pragma unroll
    for (int tt = 0; tt < 4; ++tt) {
      #pragma unroll
      for (int q = 0; q < 32; q += 4) {
        float4 wv = ld4(Wee + tt * 256 + kb + q);
        s[tt] = fmaf(e[q+0], wv.x, s[tt]);
        s[tt] = fmaf(e[q+1], wv.y, s[tt]);
        s[tt] = fmaf(e[q+2], wv.z, s[tt]);
        s[tt] = fmaf(e[q+3], wv.w, s[tt]);
      }
    }
    #pragma unroll
    for (int off = 1; off < 8; off <<= 1) {
      s[0] += __shfl_xor(s[0], off);
      s[1] += __shfl_xor(s[1], off);
      s[2] += __shfl_xor(s[2], off);
      s[3] += __shfl_xor(s[3], off);
    }
    if (sub < 4) {
      const float v = s[sub] + bee[sub];
      see[row][sub] = v;
      ee_g[(i * 128 + jh * 64 + row) * 4 + sub] = v;
    }
    const int swz = (row & 7) << 4;
    #pragma unroll
    for (int h4 = 0; h4 < 4; ++h4) {
      uint4 wv;
      wv.x = pack2(e[h4*8+0], e[h4*8+1]);
      wv.y = pack2(e[h4*8+2], e[h4*8+3]);
      wv.z = pack2(e[h4*8+4], e[h4*8+5]);
      wv.w = pack2(e[h4*8+6], e[h4*8+7]);
      *reinterpret_cast<uint4*>(sEL + ((row * 512 + kb * 2 + h4 * 16) ^ swz)) = wv;
    }
  }
  if (t < 64) sexf[t] = exlog[jh * 64 + t];
  __syncthreads();

  // ---- MFMA: 4 row-tiles x 2 cols, K=256
  f32x4 acc[4][2];
  #pragma unroll
  for (int rt = 0; rt < 4; ++rt)
    #pragma unroll
    for (int ct = 0; ct < 2; ++ct)
      acc[rt][ct] = (f32x4){0.f, 0.f, 0.f, 0.f};

  const int swz0 = (lr & 7) << 4;
  #pragma unroll
  for (int kc = 0; kc < 8; ++kc) {
    const int kbyte = kc * 64 + lk * 16;
    bf16x8 bf0 = *reinterpret_cast<const bf16x8*>(W36F + (kc * 16 + w * 2 + 0) * 512 + l * 8);
    bf16x8 bf1 = *reinterpret_cast<const bf16x8*>(W36F + (kc * 16 + w * 2 + 1) * 512 + l * 8);
    #pragma unroll
    for (int rt = 0; rt < 4; ++rt) {
      bf16x8 af = *reinterpret_cast<const bf16x8*>(
          sEL + (((rt * 16 + lr) * 512 + kbyte) ^ swz0));
      acc[rt][0] = __builtin_amdgcn_mfma_f32_16x16x32_bf16(af, bf0, acc[rt][0], 0, 0, 0);
      acc[rt][1] = __builtin_amdgcn_mfma_f32_16x16x32_bf16(af, bf1, acc[rt][1], 0, 0, 0);
    }
  }

  // ---- fused epilogue
  float am0 = 0.f, am1 = 0.f;
  #pragma unroll
  for (int rt = 0; rt < 4; ++rt) {
    #pragma unroll
    for (int q = 0; q < 4; ++q) {
      const int jrow = rt * 16 + lk * 4 + q;
      const int j = jh * 64 + jrow;
      if (exi && (sexf[jrow] > 0.f)) {
        const float e0 = see[jrow][0], e1 = see[jrow][1];
        const float e2 = see[jrow][2], e3 = see[jrow][3];
        const float pb0 = b10 + a2[j * 256 + c0] + acc[rt][0][q];
        const float pb1 = b11 + a2[j * 256 + c1] + acc[rt][1][q];
        if (e0 > 0.f) { am0 = fmaxf(am0, fmaxf(fmaf(e0, w40[0], pb0), 0.f));
                        am1 = fmaxf(am1, fmaxf(fmaf(e0, w41[0], pb1), 0.f)); }
        if (e1 > 0.f) { am0 = fmaxf(am0, fmaxf(fmaf(e1, w40[1], pb0), 0.f));
                        am1 = fmaxf(am1, fmaxf(fmaf(e1, w41[1], pb1), 0.f)); }
        if (e2 > 0.f) { am0 = fmaxf(am0, fmaxf(fmaf(e2, w40[2], pb0), 0.f));
                        am1 = fmaxf(am1, fmaxf(fmaf(e2, w41[2], pb1), 0.f)); }
        if (e3 > 0.f) { am0 = fmaxf(am0, fmaxf(fmaf(e3, w40[3], pb0), 0.f));
                        am1 = fmaxf(am1, fmaxf(fmaf(e3, w41[3], pb1), 0.f)); }
      }
    }
  }
  am0 = fmaxf(am0, __shfl_xor(am0, 16));
  am0 = fmaxf(am0, __shfl_xor(am0, 32));
  am1 = fmaxf(am1, __shfl_xor(am1, 16));
  am1 = fmaxf(am1, __shfl_xor(am1, 32));
  if (lk == 0) {  // values >= 0: float bits monotone as uint; max is exact
    atomicMax((unsigned int*)&cf1[i * 256 + c0], __float_as_uint(am0));
    atomicMax((unsigned int*)&cf1[i * 256 + c1], __float_as_uint(am1));
  }
}

// ---------------------------------------------------------------------------
// K4: gemm1, 64 j-rows per block (halves W768F L2 traffic).
// grid 256 = (i, j-half), 512 thr. LDS tile 64 x 768 bf16 = 96 KB (gfx950
// allows >64KB static LDS; 1 block/CU). K=768: [el | cf1_j | cf1_i] @
// [W3_1; W2_1; W1_1]. Epilogue -> atomicMax into cf2.
// ---------------------------------------------------------------------------
__global__ void __launch_bounds__(512) k_gemm1(
    const float* __restrict__ Arow, const float* __restrict__ Brow,
    const float* __restrict__ bel, const unsigned short* __restrict__ W768F,
    const float* __restrict__ cf1,
    const float* __restrict__ Wop1, const float* __restrict__ bop1,
    const float* __restrict__ exlog, const float* __restrict__ ee_g,
    float* __restrict__ cf2)
{
  const int i  = blockIdx.x >> 1;
  const int jh = blockIdx.x & 1;
  const int t  = threadIdx.x;
  const int w  = t >> 6;
  const int l  = t & 63;
  __shared__ char sEL[64 * 1536];       // 96 KB
  __shared__ float see[64][4];
  __shared__ float sexf[64];

  const bool exi = exlog[i] > 0.f;
  const int lr = l & 15, lk = l >> 4;
  const int c0 = w * 32 + lr, c1 = c0 + 16;
  const float b10 = bop1[c0];
  const float b11 = bop1[c1];
  float w40[4], w41[4];
  #pragma unroll
  for (int q = 0; q < 4; ++q) {
    w40[q] = Wop1[(768 + q) * 256 + c0];
    w41[q] = Wop1[(768 + q) * 256 + c1];
  }
  if (t < 256)
    see[t >> 2][t & 3] = ee_g[(i * 128 + jh * 64 + (t >> 2)) * 4 + (t & 3)];
  if (t < 64) sexf[t] = exlog[jh * 64 + t];

  // ---- stage [el | cf1_j | cf1_i]: row = t>>3, 32 k's per segment
  {
    const int row = t >> 3;
    const int sub = t & 7;
    const int kb  = sub * 32;
    const int swz = (row & 7) << 4;
    {
      const float* Ap  = Arow + i * 256 + kb;
      const float* Bp  = Brow + (jh * 64 + row) * 256 + kb;
      const float* blp = bel + kb;
      float e[32];
      #pragma unroll
      for (int q = 0; q < 32; q += 4) {
        float4 av = ld4(Ap + q), bv = ld4(Bp + q), lv = ld4(blp + q);
        e[q+0] = fmaxf(av.x + bv.x + lv.x, 0.f);
        e[q+1] = fmaxf(av.y + bv.y + lv.y, 0.f);
        e[q+2] = fmaxf(av.z + bv.z + lv.z, 0.f);
        e[q+3] = fmaxf(av.w + bv.w + lv.w, 0.f);
      }
      #pragma unroll
      for (int h4 = 0; h4 < 4; ++h4) {
        uint4 wv;
        wv.x = pack2(e[h4*8+0], e[h4*8+1]);
        wv.y = pack2(e[h4*8+2], e[h4*8+3]);
        wv.z = pack2(e[h4*8+4], e[h4*8+5]);
        wv.w = pack2(e[h4*8+6], e[h4*8+7]);
        *reinterpret_cast<uint4*>(sEL + ((row * 1536 + kb * 2 + h4 * 16) ^ swz)) = wv;
      }
    }
    {
      const float* cj = cf1 + (jh * 64 + row) * 256 + kb;
      #pragma unroll
      for (int h4 = 0; h4 < 4; ++h4) {
        float4 v0 = ld4(cj + h4 * 8), v1 = ld4(cj + h4 * 8 + 4);
        uint4 wv;
        wv.x = pack2(v0.x, v0.y); wv.y = pack2(v0.z, v0.w);
        wv.z = pack2(v1.x, v1.y); wv.w = pack2(v1.z, v1.w);
        *reinterpret_cast<uint4*>(sEL + ((row * 1536 + 512 + kb * 2 + h4 * 16) ^ swz)) = wv;
      }
    }
    {
      const float* ci = cf1 + i * 256 + kb;
      #pragma unroll
      for (int h4 = 0; h4 < 4; ++h4) {
        float4 v0 = ld4(ci + h4 * 8), v1 = ld4(ci + h4 * 8 + 4);
        uint4 wv;
        wv.x = pack2(v0.x, v0.y); wv.y = pack2(v0.z, v0.w);
        wv.z = pack2(v1.x, v1.y); wv.w = pack2(v1.z, v1.w);
        *reinterpret_cast<uint4*>(sEL + ((row * 1536 + 1024 + kb * 2 + h4 * 16) ^ swz)) = wv;
      }
    }
  }
  __syncthreads();

  // ---- MFMA: 4 row-tiles x 2 cols, K=768
  f32x4 acc[4][2];
  #pragma unroll
  for (int rt = 0; rt < 4; ++rt)
    #pragma unroll
    for (int ct = 0; ct < 2; ++ct)
      acc[rt][ct] = (f32x4){0.f, 0.f, 0.f, 0.f};

  const int swz0 = (lr & 7) << 4;
  #pragma unroll
  for (int kc = 0; kc < 24; ++kc) {
    const int kbyte = kc * 64 + lk * 16;
    bf16x8 bf0 = *reinterpret_cast<const bf16x8*>(W768F + (kc * 16 + w * 2 + 0) * 512 + l * 8);
    bf16x8 bf1 = *reinterpret_cast<const bf16x8*>(W768F + (kc * 16 + w * 2 + 1) * 512 + l * 8);
    #pragma unroll
    for (int rt = 0; rt < 4; ++rt) {
      bf16x8 af = *reinterpret_cast<const bf16x8*>(
          sEL + (((rt * 16 + lr) * 1536 + kbyte) ^ swz0));
      acc[rt][0] = __builtin_amdgcn_mfma_f32_16x16x32_bf16(af, bf0, acc[rt][0], 0, 0, 0);
      acc[rt][1] = __builtin_amdgcn_mfma_f32_16x16x32_bf16(af, bf1, acc[rt][1], 0, 0, 0);
    }
  }

  // ---- epilogue: acc already holds a1+a2+el@W3
  float am0 = 0.f, am1 = 0.f;
  #pragma unroll
  for (int rt = 0; rt < 4; ++rt) {
    #pragma unroll
    for (int q = 0; q < 4; ++q) {
      const int jrow = rt * 16 + lk * 4 + q;
      if (exi && (sexf[jrow] > 0.f)) {
        const float e0 = see[jrow][0], e1 = see[jrow][1];
        const float e2 = see[jrow][2], e3 = see[jrow][3];
        const float pb0 = b10 + acc[rt][0][q];
        const float pb1 = b11 + acc[rt][1][q];
        if (e0 > 0.f) { am0 = fmaxf(am0, fmaxf(fmaf(e0, w40[0], pb0), 0.f));
                        am1 = fmaxf(am1, fmaxf(fmaf(e0, w41[0], pb1), 0.f)); }
        if (e1 > 0.f) { am0 = fmaxf(am0, fmaxf(fmaf(e1, w40[1], pb0), 0.f));
                        am1 = fmaxf(am1, fmaxf(fmaf(e1, w41[1], pb1), 0.f)); }
        if (e2 > 0.f) { am0 = fmaxf(am0, fmaxf(fmaf(e2, w40[2], pb0), 0.f));
                        am1 = fmaxf(am1, fmaxf(fmaf(e2, w41[2], pb1), 0.f)); }
        if (e3 > 0.f) { am0 = fmaxf(am0, fmaxf(fmaf(e3, w40[3], pb0), 0.f));
                        am1 = fmaxf(am1, fmaxf(fmaf(e3, w41[3], pb1), 0.f)); }
      }
    }
  }
  am0 = fmaxf(am0, __shfl_xor(am0, 16));
  am0 = fmaxf(am0, __shfl_xor(am0, 32));
  am1 = fmaxf(am1, __shfl_xor(am1, 16));
  am1 = fmaxf(am1, __shfl_xor(am1, 32));
  if (lk == 0) {
    atomicMax((unsigned int*)&cf2[i * 256 + c0], __float_as_uint(am0));
    atomicMax((unsigned int*)&cf2[i * 256 + c1], __float_as_uint(am1));
  }
}

// ---------------------------------------------------------------------------
// K5: ch/sem/feats from [cf0|cf1|cf2]. grid 128 (m) x 512 thr (8-way K-split).
// ---------------------------------------------------------------------------
__global__ void __launch_bounds__(512) k_final(
    const float* __restrict__ cf0, const float* __restrict__ cf1,
    const float* __restrict__ cf2,
    const float* __restrict__ Wch, const float* __restrict__ bch,
    const float* __restrict__ Wsem, const float* __restrict__ bsem,
    const float* __restrict__ Wch2, const float* __restrict__ bch2,
    float* __restrict__ out_feats, float* __restrict__ out_sem)
{
  const int m  = blockIdx.x;
  const int t  = threadIdx.x;
  const int hq = (t & 63) << 2;
  const int kg = t >> 6;            // 0..7
  __shared__ float sall[768];
  __shared__ float sch[256];
  __shared__ float red[8][256];
  __shared__ float redS[8][64];

  if (t < 256) {
    sall[t]       = cf0[m * 256 + t];
    sall[256 + t] = cf1[m * 256 + t];
    sall[512 + t] = cf2[m * 256 + t];
  }
  __syncthreads();

  {
    float4 acc = make_float4(0.f, 0.f, 0.f, 0.f);
    const int k0 = kg * 96;
    #pragma unroll 8
    for (int k = k0; k < k0 + 96; ++k)
      acc = fma4(sall[k], ld4(Wch + k * 256 + hq), acc);
    st4(&red[kg][hq], acc);
  }
  __syncthreads();
  if (kg == 0) {
    float4 r = ld4(&red[0][hq]);
    #pragma unroll
    for (int g2 = 1; g2 < 8; ++g2) r = add4(r, ld4(&red[g2][hq]));
    r = relu4(add4(r, ld4(bch + hq)));
    st4(&sch[hq], r);
  }
  __syncthreads();

  {
    float4 f = make_float4(0.f, 0.f, 0.f, 0.f);
    const int k0 = kg * 32;
    #pragma unroll 8
    for (int k = k0; k < k0 + 32; ++k)
      f = fma4(sch[k], ld4(Wch2 + k * 256 + hq), f);
    const int s = t & 63;
    float sv = 0.f;
    if (s < 57) {
      #pragma unroll 8
      for (int k = k0; k < k0 + 32; ++k)
        sv = fmaf(sch[k], Wsem[k * 57 + s], sv);
    }
    redS[kg][s] = sv;
    st4(&red[kg][hq], f);
  }
  __syncthreads();
  if (kg == 0) {
    float4 r = ld4(&red[0][hq]);
    #pragma unroll
    for (int g2 = 1; g2 < 8; ++g2) r = add4(r, ld4(&red[g2][hq]));
    r = relu4(add4(r, ld4(bch2 + hq)));
    st4(&out_feats[m * 256 + hq], r);
  }
  if (t < 57) {
    float s2 = bsem[t];
    #pragma unroll
    for (int g2 = 0; g2 < 8; ++g2) s2 += redS[g2][t];
    out_sem[m * 57 + t] = s2;
  }
}

// ---------------------------------------------------------------------------
extern "C" void kernel_launch(void* const* d_in, const int* in_sizes, int n_in,
                              void* d_out, int out_size, void* d_ws, size_t ws_size,
                              hipStream_t stream)
{
  const float* pf   = (const float*)d_in[0];
  const float* Wp   = (const float*)d_in[1];
  const float* bp   = (const float*)d_in[2];
  const float* Wex  = (const float*)d_in[3];
  const float* bex  = (const float*)d_in[4];
  const float* Wel  = (const float*)d_in[5];
  const float* bel  = (const float*)d_in[6];
  const float* Wee  = (const float*)d_in[7];
  const float* bee  = (const float*)d_in[8];
  const float* Wop  = (const float*)d_in[9];
  const float* bop  = (const float*)d_in[10];
  const float* Wch  = (const float*)d_in[11];
  const float* bch  = (const float*)d_in[12];
  const float* Wsem = (const float*)d_in[13];
  const float* bsem = (const float*)d_in[14];
  const float* Wch2 = (const float*)d_in[15];
  const float* bch2 = (const float*)d_in[16];

  // Output layout (fp32): feats | sem | exists | ee
  float* out_feats = (float*)d_out;
  float* out_sem   = out_feats + M_ * F_;
  float* out_ex    = out_sem + M_ * NSEM_;
  float* out_ee    = out_ex + M_;

  // Workspace (floats)
  float* ws = (float*)d_ws;
  float* cf0 = ws;                     // 32768
  float* cf1 = ws + 32768;             // 32768 (atomicMax target, zeroed in stage1)
  float* cf2 = ws + 65536;             // 32768 (atomicMax target, zeroed in stage1)
  float* Ab  = ws + 98304;             // 32768
  float* Bb  = ws + 131072;            // 32768
  float* a1  = ws + 163840;            // 32768
  float* a2  = ws + 196608;            // 32768
  float* part = ws + 229376;           // 32*32768 = 1048576 floats (4 MB)
  unsigned short* W36F  = (unsigned short*)(ws + 1277952);  // 65536 bf16
  unsigned short* W768F = (unsigned short*)(ws + 1310720);  // 196608 bf16

  const float* Wop0 = Wop;               // iteration 0 block (772*256 floats)
  const float* Wop1 = Wop + 197632;      // iteration 1 block

  k_parent<<<1024, 256, 0, stream>>>(pf, Wp, Wop, part, W36F, W768F);
  k_stage1<<<128, 512, 0, stream>>>(part, bp, Wel, Wop0, Wex, bex,
                                    cf0, Ab, Bb, a1, a2, cf1, cf2, out_ex);
  k_gemm0<<<256, 512, 0, stream>>>(Ab, Bb, bel, W36F, Wee, bee,
                                   a1, a2, Wop0, bop, out_ex, out_ee, cf1);
  k_gemm1<<<256, 512, 0, stream>>>(Ab, Bb, bel, W768F, cf1,
                                   Wop1, bop + 256, out_ex, out_ee, cf2);
  k_final<<<128, 512, 0, stream>>>(cf0, cf1, cf2, Wch, bch, Wsem, bsem,
                                   Wch2, bch2, out_feats, out_sem);
}

// Round 10
// 65.388 us; speedup vs baseline: 1.2604x; 1.2604x over previous
//
#include <hip/hip_runtime.h>
#include <hip/hip_bf16.h>

// Shapes: M=128, H=256, F=256, T=4, I=2, NSEM=57
#define M_ 128
#define H_ 256
#define F_ 256
#define T_ 4
#define NSEM_ 57

typedef __attribute__((ext_vector_type(8))) short bf16x8;
typedef __attribute__((ext_vector_type(4))) float f32x4;

__device__ __forceinline__ float4 ld4(const float* p) { return *reinterpret_cast<const float4*>(p); }
__device__ __forceinline__ void st4(float* p, float4 v) { *reinterpret_cast<float4*>(p) = v; }
__device__ __forceinline__ float4 add4(float4 a, float4 b) { return make_float4(a.x+b.x, a.y+b.y, a.z+b.z, a.w+b.w); }
__device__ __forceinline__ float4 relu4(float4 a) { return make_float4(fmaxf(a.x,0.f), fmaxf(a.y,0.f), fmaxf(a.z,0.f), fmaxf(a.w,0.f)); }
__device__ __forceinline__ float4 fma4(float s, float4 w, float4 c) { return make_float4(fmaf(s,w.x,c.x), fmaf(s,w.y,c.y), fmaf(s,w.z,c.z), fmaf(s,w.w,c.w)); }

__device__ __forceinline__ unsigned short f2bfu(float x) {
  unsigned u = __float_as_uint(x);
  return (unsigned short)((u + 0x7FFFu + ((u >> 16) & 1u)) >> 16);  // RNE
}
__device__ __forceinline__ unsigned pack2(float lo, float hi) {
  return (unsigned)f2bfu(lo) | ((unsigned)f2bfu(hi) << 16);
}

// ---------------------------------------------------------------------------
// K1: parent partial matmul + W-frag bf16 packing.
// grid 1024 = 32 col-blocks x 32 k-chunks (8 k each), 256 thr.
// W-pack via LDS-staged 16x16 tile: coalesced 64B global reads, padded LDS.
// ---------------------------------------------------------------------------
__global__ void __launch_bounds__(256) k_parent(
    const float* __restrict__ pf, const float* __restrict__ Wp,
    const float* __restrict__ Wop, float* __restrict__ part,
    unsigned short* __restrict__ W36F, unsigned short* __restrict__ W768F)
{
  const int t = threadIdx.x;
  __shared__ float spf[8];
  __shared__ float tile[16][17];

  // fb_global = b>>1 in [0, 512): [0,128) -> W36F (it0), [128,512) -> W768F.
  const int fbg = blockIdx.x >> 1;
  const int half = blockIdx.x & 1;
  const bool it0 = fbg < 128;
  const int fb = it0 ? fbg : fbg - 128;
  const int kk = fb >> 4, ct = fb & 15;
  const int base_k = kk * 32 + half * 16;
  int row_base;
  if (it0) row_base = 512 + base_k;                 // W3_0
  else row_base = (base_k < 256) ? 512 + base_k     // W3_1
                : (base_k < 512 ? base_k : base_k - 512);  // W2_1 / W1_1
  const float* wsrc = Wop + (it0 ? 0 : 197632);
  {
    const int r = t >> 4, c = t & 15;
    tile[r][c] = wsrc[(size_t)(row_base + r) * 256 + ct * 16 + c];
  }

  const int cb = (blockIdx.x & 31) * 1024 + t * 4;
  const int kc = blockIdx.x >> 5;
  if (t < 8) spf[t] = pf[kc * 8 + t];
  __syncthreads();
  const float* w = Wp + (size_t)kc * 8 * 32768 + cb;
  float4 acc = make_float4(0.f, 0.f, 0.f, 0.f);
  #pragma unroll
  for (int k = 0; k < 8; ++k)
    acc = fma4(spf[k], ld4(w + (size_t)k * 32768), acc);
  st4(&part[kc * 32768 + cb], acc);

  {
    const int k_local = ((t >> 7) << 3) + (t & 7);
    const int h_local = (t >> 3) & 15;
    const int e = half * 256 + t;
    unsigned short v = f2bfu(tile[k_local][h_local]);
    if (it0) W36F[fb * 512 + e] = v;
    else     W768F[fb * 512 + e] = v;
  }
}

// ---------------------------------------------------------------------------
// K2: stage1 = combine(32 partials) + A/B + a1/a2(it0) + exists + zero cf1/cf2.
// grid 256 = (m, sel), 256 thr. Full unroll: 32 part loads in flight.
// ---------------------------------------------------------------------------
__global__ void __launch_bounds__(256) k_stage1(
    const float* __restrict__ part, const float* __restrict__ bp,
    const float* __restrict__ Wel, const float* __restrict__ Wop0,
    const float* __restrict__ Wex, const float* __restrict__ bex,
    float* __restrict__ cf0, float* __restrict__ A, float* __restrict__ B,
    float* __restrict__ a1, float* __restrict__ a2,
    float* __restrict__ cf1, float* __restrict__ cf2,
    float* __restrict__ out_ex)
{
  const int m = blockIdx.x >> 1, sel = blockIdx.x & 1;
  const int t = threadIdx.x;
  __shared__ float sall[256];
  __shared__ float red[2][4][256];
  __shared__ float redE[4];

  // zero atomicMax targets for this call (poison/stale-replay safety)
  (sel ? cf2 : cf1)[m * 256 + t] = 0.f;

  float pv[32];
  #pragma unroll
  for (int q = 0; q < 32; ++q) pv[q] = part[q * 32768 + m * 256 + t];
  float v = bp[m * 256 + t];
  #pragma unroll
  for (int q = 0; q < 32; ++q) v += pv[q];
  v = fmaxf(v, 0.f);
  sall[t] = v;
  if (sel == 0) {
    cf0[m * 256 + t] = v;
    float p = v * Wex[t];
    #pragma unroll
    for (int off = 32; off > 0; off >>= 1) p += __shfl_xor(p, off);
    if ((t & 63) == 0) redE[t >> 6] = p;
  }
  __syncthreads();

  const float* W0 = Wel  + (sel ? 65536 : 0);
  const float* W1 = Wop0 + (sel ? 65536 : 0);
  const int hq = (t & 63) << 2, kg = t >> 6, k0 = kg * 64;
  float4 acc0 = make_float4(0.f, 0.f, 0.f, 0.f), acc1 = acc0;
  #pragma unroll 8
  for (int k = k0; k < k0 + 64; ++k) {
    const float s = sall[k];
    acc0 = fma4(s, ld4(W0 + k * 256 + hq), acc0);
    acc1 = fma4(s, ld4(W1 + k * 256 + hq), acc1);
  }
  st4(&red[0][kg][hq], acc0);
  st4(&red[1][kg][hq], acc1);
  __syncthreads();
  if (kg < 2) {
    float4 r = add4(add4(ld4(&red[kg][0][hq]), ld4(&red[kg][1][hq])),
                    add4(ld4(&red[kg][2][hq]), ld4(&red[kg][3][hq])));
    float* dst = (kg == 0) ? (sel ? B : A) : (sel ? a2 : a1);
    st4(&dst[m * 256 + hq], r);
  }
  if (sel == 0 && t == 0)
    out_ex[m] = redE[0] + redE[1] + redE[2] + redE[3] + bex[0];
}

// ---------------------------------------------------------------------------
// K3: gemm0 = EL tile (fp32) -> ee (fp32, written once) + bf16 MFMA el@W3_0
// (K=256, depth-1 pipelined frag loads) + fused masked relu-max epilogue
// (operands hoisted above barrier) -> atomicMax into cf1.
// grid 512 = (i, jq), 512 thr = 8 waves.
// ---------------------------------------------------------------------------
__global__ void __launch_bounds__(512) k_gemm0(
    const float* __restrict__ Arow, const float* __restrict__ Brow,
    const float* __restrict__ bel, const unsigned short* __restrict__ W36F,
    const float* __restrict__ Wee, const float* __restrict__ bee,
    const float* __restrict__ a1, const float* __restrict__ a2,
    const float* __restrict__ Wop0, const float* __restrict__ bop0,
    const float* __restrict__ exlog,
    float* __restrict__ ee_g, float* __restrict__ cf1)
{
  const int i  = blockIdx.x >> 2;
  const int jq = blockIdx.x & 3;
  const int t  = threadIdx.x;
  const int w  = t >> 6;
  const int l  = t & 63;
  __shared__ char sEL[32 * 512];
  __shared__ float see[32][4];
  __shared__ float sexf[32];

  const bool exi = exlog[i] > 0.f;
  const int lr = l & 15, lk = l >> 4;

  // ---- hoisted epilogue operands (issue early, consumed after MFMA)
  const int c0 = w * 32 + lr, c1 = c0 + 16;
  const float b10 = a1[i * 256 + c0] + bop0[c0];
  const float b11 = a1[i * 256 + c1] + bop0[c1];
  float w40[4], w41[4], a2v0[8], a2v1[8];
  #pragma unroll
  for (int tt = 0; tt < 4; ++tt) {
    w40[tt] = Wop0[(768 + tt) * 256 + c0];
    w41[tt] = Wop0[(768 + tt) * 256 + c1];
  }
  #pragma unroll
  for (int jt = 0; jt < 2; ++jt)
    #pragma unroll
    for (int q = 0; q < 4; ++q) {
      const int j = jq * 32 + jt * 16 + lk * 4 + q;
      a2v0[jt * 4 + q] = a2[j * 256 + c0];
      a2v1[jt * 4 + q] = a2[j * 256 + c1];
    }

  // ---- stage EL tile (fp32) + ee + pack bf16
  {
    const int row = t >> 4;
    const int sub = t & 15;
    const int kb  = sub * 16;
    const float* Ap  = Arow + i * 256 + kb;
    const float* Bp  = Brow + (jq * 32 + row) * 256 + kb;
    const float* blp = bel + kb;
    float e[16];
    #pragma unroll
    for (int q = 0; q < 16; q += 4) {
      float4 av = ld4(Ap + q), bv = ld4(Bp + q), lv = ld4(blp + q);
      e[q+0] = fmaxf(av.x + bv.x + lv.x, 0.f);
      e[q+1] = fmaxf(av.y + bv.y + lv.y, 0.f);
      e[q+2] = fmaxf(av.z + bv.z + lv.z, 0.f);
      e[q+3] = fmaxf(av.w + bv.w + lv.w, 0.f);
    }
    float s[4] = {0.f, 0.f, 0.f, 0.f};
    #pragma unroll
    for (int tt = 0; tt < 4; ++tt) {
      #pragma unroll
      for (int q = 0; q < 16; q += 4) {
        float4 wv = ld4(Wee + tt * 256 + kb + q);
        s[tt] = fmaf(e[q+0], wv.x, s[tt]);
        s[tt] = fmaf(e[q+1], wv.y, s[tt]);
        s[tt] = fmaf(e[q+2], wv.z, s[tt]);
        s[tt] = fmaf(e[q+3], wv.w, s[tt]);
      }
    }
    #pragma unroll
    for (int off = 1; off < 16; off <<= 1) {
      s[0] += __shfl_xor(s[0], off);
      s[1] += __shfl_xor(s[1], off);
      s[2] += __shfl_xor(s[2], off);
      s[3] += __shfl_xor(s[3], off);
    }
    if (sub < 4) {
      const float v = s[sub] + bee[sub];
      see[row][sub] = v;
      ee_g[(i * 128 + jq * 32 + row) * 4 + sub] = v;
    }
    const int swz = (row & 7) << 4;
    uint4 w0, w1;
    w0.x = pack2(e[0], e[1]);  w0.y = pack2(e[2], e[3]);
    w0.z = pack2(e[4], e[5]);  w0.w = pack2(e[6], e[7]);
    w1.x = pack2(e[8], e[9]);  w1.y = pack2(e[10], e[11]);
    w1.z = pack2(e[12], e[13]); w1.w = pack2(e[14], e[15]);
    *reinterpret_cast<uint4*>(sEL + ((row * 512 + kb * 2)      ^ swz)) = w0;
    *reinterpret_cast<uint4*>(sEL + ((row * 512 + kb * 2 + 16) ^ swz)) = w1;
  }
  if (t < 32) sexf[t] = exlog[jq * 32 + t];
  __syncthreads();

  // ---- MFMA: depth-1 pipelined loads (frags from L2, A from LDS)
  f32x4 acc[2][2];
  #pragma unroll
  for (int jt = 0; jt < 2; ++jt)
    #pragma unroll
    for (int ct = 0; ct < 2; ++ct)
      acc[jt][ct] = (f32x4){0.f, 0.f, 0.f, 0.f};

  const int swz0 = (lr & 7) << 4;
  bf16x8 cb0 = *reinterpret_cast<const bf16x8*>(W36F + (0 * 16 + w * 2 + 0) * 512 + l * 8);
  bf16x8 cb1 = *reinterpret_cast<const bf16x8*>(W36F + (0 * 16 + w * 2 + 1) * 512 + l * 8);
  bf16x8 ca0 = *reinterpret_cast<const bf16x8*>(sEL + ((lr * 512 + lk * 16) ^ swz0));
  bf16x8 ca1 = *reinterpret_cast<const bf16x8*>(sEL + (((16 + lr) * 512 + lk * 16) ^ swz0));
  #pragma unroll
  for (int kc = 0; kc < 8; ++kc) {
    bf16x8 nb0, nb1, na0, na1;
    if (kc < 7) {
      const int kbyte = (kc + 1) * 64 + lk * 16;
      nb0 = *reinterpret_cast<const bf16x8*>(W36F + ((kc + 1) * 16 + w * 2 + 0) * 512 + l * 8);
      nb1 = *reinterpret_cast<const bf16x8*>(W36F + ((kc + 1) * 16 + w * 2 + 1) * 512 + l * 8);
      na0 = *reinterpret_cast<const bf16x8*>(sEL + ((lr * 512 + kbyte) ^ swz0));
      na1 = *reinterpret_cast<const bf16x8*>(sEL + (((16 + lr) * 512 + kbyte) ^ swz0));
    }
    acc[0][0] = __builtin_amdgcn_mfma_f32_16x16x32_bf16(ca0, cb0, acc[0][0], 0, 0, 0);
    acc[1][0] = __builtin_amdgcn_mfma_f32_16x16x32_bf16(ca1, cb0, acc[1][0], 0, 0, 0);
    acc[0][1] = __builtin_amdgcn_mfma_f32_16x16x32_bf16(ca0, cb1, acc[0][1], 0, 0, 0);
    acc[1][1] = __builtin_amdgcn_mfma_f32_16x16x32_bf16(ca1, cb1, acc[1][1], 0, 0, 0);
    if (kc < 7) { cb0 = nb0; cb1 = nb1; ca0 = na0; ca1 = na1; }
  }

  // ---- fused epilogue
  float am0 = 0.f, am1 = 0.f;
  #pragma unroll
  for (int jt = 0; jt < 2; ++jt) {
    #pragma unroll
    for (int q = 0; q < 4; ++q) {
      const int jrow = jt * 16 + lk * 4 + q;
      if (exi && (sexf[jrow] > 0.f)) {
        const float e0 = see[jrow][0], e1 = see[jrow][1];
        const float e2 = see[jrow][2], e3 = see[jrow][3];
        const float pb0 = b10 + a2v0[jt * 4 + q] + acc[jt][0][q];
        const float pb1 = b11 + a2v1[jt * 4 + q] + acc[jt][1][q];
        if (e0 > 0.f) { am0 = fmaxf(am0, fmaxf(fmaf(e0, w40[0], pb0), 0.f));
                        am1 = fmaxf(am1, fmaxf(fmaf(e0, w41[0], pb1), 0.f)); }
        if (e1 > 0.f) { am0 = fmaxf(am0, fmaxf(fmaf(e1, w40[1], pb0), 0.f));
                        am1 = fmaxf(am1, fmaxf(fmaf(e1, w41[1], pb1), 0.f)); }
        if (e2 > 0.f) { am0 = fmaxf(am0, fmaxf(fmaf(e2, w40[2], pb0), 0.f));
                        am1 = fmaxf(am1, fmaxf(fmaf(e2, w41[2], pb1), 0.f)); }
        if (e3 > 0.f) { am0 = fmaxf(am0, fmaxf(fmaf(e3, w40[3], pb0), 0.f));
                        am1 = fmaxf(am1, fmaxf(fmaf(e3, w41[3], pb1), 0.f)); }
      }
    }
  }
  am0 = fmaxf(am0, __shfl_xor(am0, 16));
  am0 = fmaxf(am0, __shfl_xor(am0, 32));
  am1 = fmaxf(am1, __shfl_xor(am1, 16));
  am1 = fmaxf(am1, __shfl_xor(am1, 32));
  if (lk == 0) {  // values >= 0: float bits monotone as uint; max is exact
    atomicMax((unsigned int*)&cf1[i * 256 + c0], __float_as_uint(am0));
    atomicMax((unsigned int*)&cf1[i * 256 + c1], __float_as_uint(am1));
  }
}

// ---------------------------------------------------------------------------
// K4: gemm1 = K=768 MFMA [el_ij | cf1_j | cf1_i] @ [W3_1; W2_1; W1_1] +
// masked relu-max epilogue -> atomicMax into cf2. Pipelined like gemm0.
// grid 512 = (i, jq), 512 thr. LDS 32 x 768 bf16 (48 KB), XOR-swizzled.
// ---------------------------------------------------------------------------
__global__ void __launch_bounds__(512) k_gemm1(
    const float* __restrict__ Arow, const float* __restrict__ Brow,
    const float* __restrict__ bel, const unsigned short* __restrict__ W768F,
    const float* __restrict__ cf1,
    const float* __restrict__ Wop1, const float* __restrict__ bop1,
    const float* __restrict__ exlog, const float* __restrict__ ee_g,
    float* __restrict__ cf2)
{
  const int i  = blockIdx.x >> 2;
  const int jq = blockIdx.x & 3;
  const int t  = threadIdx.x;
  const int w  = t >> 6;
  const int l  = t & 63;
  __shared__ char sEL[32 * 1536];
  __shared__ float see[32][4];
  __shared__ float sexf[32];

  const bool exi = exlog[i] > 0.f;
  const int lr = l & 15, lk = l >> 4;

  // ---- hoisted epilogue operands
  const int c0 = w * 32 + lr, c1 = c0 + 16;
  const float b10 = bop1[c0];
  const float b11 = bop1[c1];
  float w40[4], w41[4];
  #pragma unroll
  for (int tt = 0; tt < 4; ++tt) {
    w40[tt] = Wop1[(768 + tt) * 256 + c0];
    w41[tt] = Wop1[(768 + tt) * 256 + c1];
  }
  if (t < 128)
    see[t >> 2][t & 3] = ee_g[(i * 128 + jq * 32 + (t >> 2)) * 4 + (t & 3)];
  if (t < 32) sexf[t] = exlog[jq * 32 + t];

  // ---- stage [el | cf1_j | cf1_i] tile
  {
    const int row = t >> 4;
    const int sub = t & 15;
    const int kb  = sub * 16;
    const int swz = (row & 7) << 4;
    {
      const float* Ap  = Arow + i * 256 + kb;
      const float* Bp  = Brow + (jq * 32 + row) * 256 + kb;
      const float* blp = bel + kb;
      float e[16];
      #pragma unroll
      for (int q = 0; q < 16; q += 4) {
        float4 av = ld4(Ap + q), bv = ld4(Bp + q), lv = ld4(blp + q);
        e[q+0] = fmaxf(av.x + bv.x + lv.x, 0.f);
        e[q+1] = fmaxf(av.y + bv.y + lv.y, 0.f);
        e[q+2] = fmaxf(av.z + bv.z + lv.z, 0.f);
        e[q+3] = fmaxf(av.w + bv.w + lv.w, 0.f);
      }
      uint4 w0, w1;
      w0.x = pack2(e[0], e[1]);  w0.y = pack2(e[2], e[3]);
      w0.z = pack2(e[4], e[5]);  w0.w = pack2(e[6], e[7]);
      w1.x = pack2(e[8], e[9]);  w1.y = pack2(e[10], e[11]);
      w1.z = pack2(e[12], e[13]); w1.w = pack2(e[14], e[15]);
      *reinterpret_cast<uint4*>(sEL + ((row * 1536 + kb * 2)      ^ swz)) = w0;
      *reinterpret_cast<uint4*>(sEL + ((row * 1536 + kb * 2 + 16) ^ swz)) = w1;
    }
    {
      const float* cj = cf1 + (jq * 32 + row) * 256 + kb;
      float4 v0 = ld4(cj), v1 = ld4(cj + 4), v2 = ld4(cj + 8), v3 = ld4(cj + 12);
      uint4 w0, w1;
      w0.x = pack2(v0.x, v0.y); w0.y = pack2(v0.z, v0.w);
      w0.z = pack2(v1.x, v1.y); w0.w = pack2(v1.z, v1.w);
      w1.x = pack2(v2.x, v2.y); w1.y = pack2(v2.z, v2.w);
      w1.z = pack2(v3.x, v3.y); w1.w = pack2(v3.z, v3.w);
      *reinterpret_cast<uint4*>(sEL + ((row * 1536 + 512 + kb * 2)      ^ swz)) = w0;
      *reinterpret_cast<uint4*>(sEL + ((row * 1536 + 512 + kb * 2 + 16) ^ swz)) = w1;
    }
    {
      const float* ci = cf1 + i * 256 + kb;
      float4 v0 = ld4(ci), v1 = ld4(ci + 4), v2 = ld4(ci + 8), v3 = ld4(ci + 12);
      uint4 w0, w1;
      w0.x = pack2(v0.x, v0.y); w0.y = pack2(v0.z, v0.w);
      w0.z = pack2(v1.x, v1.y); w0.w = pack2(v1.z, v1.w);
      w1.x = pack2(v2.x, v2.y); w1.y = pack2(v2.z, v2.w);
      w1.z = pack2(v3.x, v3.y); w1.w = pack2(v3.z, v3.w);
      *reinterpret_cast<uint4*>(sEL + ((row * 1536 + 1024 + kb * 2)      ^ swz)) = w0;
      *reinterpret_cast<uint4*>(sEL + ((row * 1536 + 1024 + kb * 2 + 16) ^ swz)) = w1;
    }
  }
  __syncthreads();

  // ---- MFMA K=768, depth-1 pipelined
  f32x4 acc[2][2];
  #pragma unroll
  for (int jt = 0; jt < 2; ++jt)
    #pragma unroll
    for (int ct = 0; ct < 2; ++ct)
      acc[jt][ct] = (f32x4){0.f, 0.f, 0.f, 0.f};

  const int swz0 = (lr & 7) << 4;
  bf16x8 cb0 = *reinterpret_cast<const bf16x8*>(W768F + (0 * 16 + w * 2 + 0) * 512 + l * 8);
  bf16x8 cb1 = *reinterpret_cast<const bf16x8*>(W768F + (0 * 16 + w * 2 + 1) * 512 + l * 8);
  bf16x8 ca0 = *reinterpret_cast<const bf16x8*>(sEL + ((lr * 1536 + lk * 16) ^ swz0));
  bf16x8 ca1 = *reinterpret_cast<const bf16x8*>(sEL + (((16 + lr) * 1536 + lk * 16) ^ swz0));
  #pragma unroll
  for (int kc = 0; kc < 24; ++kc) {
    bf16x8 nb0, nb1, na0, na1;
    if (kc < 23) {
      const int kbyte = (kc + 1) * 64 + lk * 16;
      nb0 = *reinterpret_cast<const bf16x8*>(W768F + ((kc + 1) * 16 + w * 2 + 0) * 512 + l * 8);
      nb1 = *reinterpret_cast<const bf16x8*>(W768F + ((kc + 1) * 16 + w * 2 + 1) * 512 + l * 8);
      na0 = *reinterpret_cast<const bf16x8*>(sEL + ((lr * 1536 + kbyte) ^ swz0));
      na1 = *reinterpret_cast<const bf16x8*>(sEL + (((16 + lr) * 1536 + kbyte) ^ swz0));
    }
    acc[0][0] = __builtin_amdgcn_mfma_f32_16x16x32_bf16(ca0, cb0, acc[0][0], 0, 0, 0);
    acc[1][0] = __builtin_amdgcn_mfma_f32_16x16x32_bf16(ca1, cb0, acc[1][0], 0, 0, 0);
    acc[0][1] = __builtin_amdgcn_mfma_f32_16x16x32_bf16(ca0, cb1, acc[0][1], 0, 0, 0);
    acc[1][1] = __builtin_amdgcn_mfma_f32_16x16x32_bf16(ca1, cb1, acc[1][1], 0, 0, 0);
    if (kc < 23) { cb0 = nb0; cb1 = nb1; ca0 = na0; ca1 = na1; }
  }

  // ---- epilogue: acc already holds a1+a2+el@W3
  float am0 = 0.f, am1 = 0.f;
  #pragma unroll
  for (int jt = 0; jt < 2; ++jt) {
    #pragma unroll
    for (int q = 0; q < 4; ++q) {
      const int jrow = jt * 16 + lk * 4 + q;
      if (exi && (sexf[jrow] > 0.f)) {
        const float e0 = see[jrow][0], e1 = see[jrow][1];
        const float e2 = see[jrow][2], e3 = see[jrow][3];
        const float pb0 = b10 + acc[jt][0][q];
        const float pb1 = b11 + acc[jt][1][q];
        if (e0 > 0.f) { am0 = fmaxf(am0, fmaxf(fmaf(e0, w40[0], pb0), 0.f));
                        am1 = fmaxf(am1, fmaxf(fmaf(e0, w41[0], pb1), 0.f)); }
        if (e1 > 0.f) { am0 = fmaxf(am0, fmaxf(fmaf(e1, w40[1], pb0), 0.f));
                        am1 = fmaxf(am1, fmaxf(fmaf(e1, w41[1], pb1), 0.f)); }
        if (e2 > 0.f) { am0 = fmaxf(am0, fmaxf(fmaf(e2, w40[2], pb0), 0.f));
                        am1 = fmaxf(am1, fmaxf(fmaf(e2, w41[2], pb1), 0.f)); }
        if (e3 > 0.f) { am0 = fmaxf(am0, fmaxf(fmaf(e3, w40[3], pb0), 0.f));
                        am1 = fmaxf(am1, fmaxf(fmaf(e3, w41[3], pb1), 0.f)); }
      }
    }
  }
  am0 = fmaxf(am0, __shfl_xor(am0, 16));
  am0 = fmaxf(am0, __shfl_xor(am0, 32));
  am1 = fmaxf(am1, __shfl_xor(am1, 16));
  am1 = fmaxf(am1, __shfl_xor(am1, 32));
  if (lk == 0) {
    atomicMax((unsigned int*)&cf2[i * 256 + c0], __float_as_uint(am0));
    atomicMax((unsigned int*)&cf2[i * 256 + c1], __float_as_uint(am1));
  }
}

// ---------------------------------------------------------------------------
// K5: ch/sem/feats from [cf0|cf1|cf2]. grid 128 (m) x 512 thr (8-way K-split).
// ---------------------------------------------------------------------------
__global__ void __launch_bounds__(512) k_final(
    const float* __restrict__ cf0, const float* __restrict__ cf1,
    const float* __restrict__ cf2,
    const float* __restrict__ Wch, const float* __restrict__ bch,
    const float* __restrict__ Wsem, const float* __restrict__ bsem,
    const float* __restrict__ Wch2, const float* __restrict__ bch2,
    float* __restrict__ out_feats, float* __restrict__ out_sem)
{
  const int m  = blockIdx.x;
  const int t  = threadIdx.x;
  const int hq = (t & 63) << 2;
  const int kg = t >> 6;            // 0..7
  __shared__ float sall[768];
  __shared__ float sch[256];
  __shared__ float red[8][256];
  __shared__ float redS[8][64];

  if (t < 256) {
    sall[t]       = cf0[m * 256 + t];
    sall[256 + t] = cf1[m * 256 + t];
    sall[512 + t] = cf2[m * 256 + t];
  }
  __syncthreads();

  {
    float4 acc = make_float4(0.f, 0.f, 0.f, 0.f);
    const int k0 = kg * 96;
    #pragma unroll 8
    for (int k = k0; k < k0 + 96; ++k)
      acc = fma4(sall[k], ld4(Wch + k * 256 + hq), acc);
    st4(&red[kg][hq], acc);
  }
  __syncthreads();
  if (kg == 0) {
    float4 r = ld4(&red[0][hq]);
    #pragma unroll
    for (int g2 = 1; g2 < 8; ++g2) r = add4(r, ld4(&red[g2][hq]));
    r = relu4(add4(r, ld4(bch + hq)));
    st4(&sch[hq], r);
  }
  __syncthreads();

  {
    float4 f = make_float4(0.f, 0.f, 0.f, 0.f);
    const int k0 = kg * 32;
    #pragma unroll 8
    for (int k = k0; k < k0 + 32; ++k)
      f = fma4(sch[k], ld4(Wch2 + k * 256 + hq), f);
    const int s = t & 63;
    float sv = 0.f;
    if (s < 57) {
      #pragma unroll 8
      for (int k = k0; k < k0 + 32; ++k)
        sv = fmaf(sch[k], Wsem[k * 57 + s], sv);
    }
    redS[kg][s] = sv;
    st4(&red[kg][hq], f);
  }
  __syncthreads();
  if (kg == 0) {
    float4 r = ld4(&red[0][hq]);
    #pragma unroll
    for (int g2 = 1; g2 < 8; ++g2) r = add4(r, ld4(&red[g2][hq]));
    r = relu4(add4(r, ld4(bch2 + hq)));
    st4(&out_feats[m * 256 + hq], r);
  }
  if (t < 57) {
    float s2 = bsem[t];
    #pragma unroll
    for (int g2 = 0; g2 < 8; ++g2) s2 += redS[g2][t];
    out_sem[m * 57 + t] = s2;
  }
}

// ---------------------------------------------------------------------------
extern "C" void kernel_launch(void* const* d_in, const int* in_sizes, int n_in,
                              void* d_out, int out_size, void* d_ws, size_t ws_size,
                              hipStream_t stream)
{
  const float* pf   = (const float*)d_in[0];
  const float* Wp   = (const float*)d_in[1];
  const float* bp   = (const float*)d_in[2];
  const float* Wex  = (const float*)d_in[3];
  const float* bex  = (const float*)d_in[4];
  const float* Wel  = (const float*)d_in[5];
  const float* bel  = (const float*)d_in[6];
  const float* Wee  = (const float*)d_in[7];
  const float* bee  = (const float*)d_in[8];
  const float* Wop  = (const float*)d_in[9];
  const float* bop  = (const float*)d_in[10];
  const float* Wch  = (const float*)d_in[11];
  const float* bch  = (const float*)d_in[12];
  const float* Wsem = (const float*)d_in[13];
  const float* bsem = (const float*)d_in[14];
  const float* Wch2 = (const float*)d_in[15];
  const float* bch2 = (const float*)d_in[16];

  // Output layout (fp32): feats | sem | exists | ee
  float* out_feats = (float*)d_out;
  float* out_sem   = out_feats + M_ * F_;
  float* out_ex    = out_sem + M_ * NSEM_;
  float* out_ee    = out_ex + M_;

  // Workspace (floats)
  float* ws = (float*)d_ws;
  float* cf0 = ws;                     // 32768
  float* cf1 = ws + 32768;             // 32768 (atomicMax target, zeroed in stage1)
  float* cf2 = ws + 65536;             // 32768 (atomicMax target, zeroed in stage1)
  float* Ab  = ws + 98304;             // 32768
  float* Bb  = ws + 131072;            // 32768
  float* a1  = ws + 163840;            // 32768
  float* a2  = ws + 196608;            // 32768
  float* part = ws + 229376;           // 32*32768 = 1048576 floats (4 MB)
  unsigned short* W36F  = (unsigned short*)(ws + 1277952);  // 65536 bf16
  unsigned short* W768F = (unsigned short*)(ws + 1310720);  // 196608 bf16

  const float* Wop0 = Wop;               // iteration 0 block (772*256 floats)
  const float* Wop1 = Wop + 197632;      // iteration 1 block

  k_parent<<<1024, 256, 0, stream>>>(pf, Wp, Wop, part, W36F, W768F);
  k_stage1<<<256, 256, 0, stream>>>(part, bp, Wel, Wop0, Wex, bex,
                                    cf0, Ab, Bb, a1, a2, cf1, cf2, out_ex);
  k_gemm0<<<512, 512, 0, stream>>>(Ab, Bb, bel, W36F, Wee, bee,
                                   a1, a2, Wop0, bop, out_ex, out_ee, cf1);
  k_gemm1<<<512, 512, 0, stream>>>(Ab, Bb, bel, W768F, cf1,
                                   Wop1, bop + 256, out_ex, out_ee, cf2);
  k_final<<<128, 512, 0, stream>>>(cf0, cf1, cf2, Wch, bch, Wsem, bsem,
                                   Wch2, bch2, out_feats, out_sem);
}